// Round 3
// baseline (369.900 us; speedup 1.0000x reference)
//
#include <hip/hip_runtime.h>

// Binarized depthwise 3x3 conv, stride 1, SAME, NHWC, sign(0)=+1.
// x: (16,112,112,256) f32, kernel: (3,3,256,1) f32, out: (16,112,112,256) f32.
//
// Round 6: R=4 multi-row waves (requested read volume 1.875x input vs 3.0x
// single-row) + 16B uint4 loads (4 ch/lane; round-2's 8B loads halved
// bytes-in-flight and left the read path 26% under the ~6.5 TB/s service
// ceiling) + byte-field-packed sign state so VGPR stays under the 64-reg
// occupancy cliff that killed round-1's identical shape (68 VGPR -> 4
// waves/SIMD).
//
// Packing: rowsig rs holds ch's sign bits in byte-field ch: bit (8*ch+p) =
// sign of input row h0-1+p (p in [0,5]). Kernel col code kj3[j]: bit
// (8*ch+i) = sign k[i][j]. For output row r: xx = (rs>>r) ^ kj3[j];
// per-channel mismatch = popc(xx & (b << 8*ch)) with 3-bit window mask b.
// Shift-by-r never crosses fields (used bits/field = 6, r <= 3).
// Border rows shrink b at compile time (dropped taps are zero-pad terms);
// border columns drop the whole j term via tag dispatch. One wave covers
// all 256 channels (64 lanes x 4 ch).

constexpr int N = 16, H = 112, W = 112, C = 256;
constexpr int TW = 8;   // output columns per wave strip; W/TW = 14
constexpr int R  = 4;   // output rows per wave; 4 waves/block -> 16 rows/block

typedef float f32x4 __attribute__((ext_vector_type(4)));

struct TrueT  { static constexpr bool value = true;  };
struct FalseT { static constexpr bool value = false; };

template<bool TOP, bool BOT>
__device__ __forceinline__ void run_tile(
        const float* __restrict__ x, const float* __restrict__ k,
        float* __restrict__ out, int n, int h0, int w0, int c0) {

    // Kernel sign codes, 4 channels in byte-fields: kj3[j] bit (8*ch + kr).
    unsigned kj3[3] = {0u, 0u, 0u};
#pragma unroll
    for (int t = 0; t < 9; ++t) {
        const uint4 kv = *reinterpret_cast<const uint4*>(k + t * C + c0);
        const int kr = t / 3, kj = t % 3;
        kj3[kj] |= ((kv.x >> 31) << kr)        | ((kv.y >> 31) << (8 + kr))
                 | ((kv.z >> 31) << (16 + kr)) | ((kv.w >> 31) << (24 + kr));
    }

    constexpr int PLO = TOP ? 1 : 0;      // input rows h0-1+p, p in [PLO,PHI]
    constexpr int PHI = BOT ? R : R + 1;

    const size_t rowstride = (size_t)W * C;
    const float* xin = x + (size_t)(n * H + (h0 - 1)) * rowstride + c0;
    float* o0 = out + (size_t)(n * H + h0) * rowstride + c0;

    // Load one x column: 6 independent 16B loads (1 KB/wave each), pack sign
    // bits of rows h0-1+p into bit (8*ch + p) of one register.
    auto colSig = [&](int cc) -> unsigned {
        unsigned rs = 0u;
        const float* cp = xin + (size_t)cc * C;
#pragma unroll
        for (int p = PLO; p <= PHI; ++p) {
            const uint4 v = *reinterpret_cast<const uint4*>(cp + (size_t)p * rowstride);
            rs |= ((v.x >> 31) << p)        | ((v.y >> 31) << (8 + p))
                | ((v.z >> 31) << (16 + p)) | ((v.w >> 31) << (24 + p));
        }
        return rs;
    };

    // Emit output column w for all R rows. rs0 = col w-1 (kernel col 0),
    // rs1 = col w (col 1), rs2 = col w+1 (col 2). jt0/jt2 drop edge terms.
    auto emit = [&](int w, unsigned rs0, unsigned rs1, unsigned rs2,
                    auto jt0, auto jt2) {
#pragma unroll
        for (int r = 0; r < R; ++r) {
            const bool border = (TOP && r == 0) || (BOT && r == R - 1);
            const unsigned b = (TOP && r == 0) ? 0x6u
                             : (BOT && r == R - 1) ? 0x3u : 0x7u;
            const int nr = border ? 2 : 3;
            int cnt0 = 0, cnt1 = 0, cnt2 = 0, cnt3 = 0, nt = 0;
            auto addj = [&](unsigned rsj, unsigned kc) {
                const unsigned xx = (rsj >> r) ^ kc;
                cnt0 += __popc(xx & b);
                cnt1 += __popc(xx & (b << 8));
                cnt2 += __popc(xx & (b << 16));
                cnt3 += __popc(xx & (b << 24));
                nt += nr;
            };
            if constexpr (decltype(jt0)::value) addj(rs0, kj3[0]);
            addj(rs1, kj3[1]);
            if constexpr (decltype(jt2)::value) addj(rs2, kj3[2]);
            f32x4 ov;
            ov[0] = (float)(nt - 2 * cnt0);
            ov[1] = (float)(nt - 2 * cnt1);
            ov[2] = (float)(nt - 2 * cnt2);
            ov[3] = (float)(nt - 2 * cnt3);
            __builtin_nontemporal_store(ov,
                reinterpret_cast<f32x4*>(o0 + (size_t)r * rowstride + (size_t)w * C));
        }
    };

    unsigned rs_m2, rs_m1, rs_c;

    rs_m2 = (w0 > 0) ? colSig(w0 - 1) : 0u;
    rs_m1 = colSig(w0);

    // First output (w = w0): left-edge strip drops the j=0 term.
    rs_c = colSig(w0 + 1);
    if (w0 > 0) emit(w0, rs_m2, rs_m1, rs_c, TrueT{},  TrueT{});
    else        emit(w0, rs_m2, rs_m1, rs_c, FalseT{}, TrueT{});
    rs_m2 = rs_m1; rs_m1 = rs_c;

    // Steady state: all taps present.
#pragma unroll 2
    for (int i = 2; i < TW; ++i) {
        rs_c = colSig(w0 + i);
        emit(w0 + i - 1, rs_m2, rs_m1, rs_c, TrueT{}, TrueT{});
        rs_m2 = rs_m1; rs_m1 = rs_c;
    }

    // Last output (w = w0+TW-1): right-edge strip drops the j=2 term.
    if (w0 + TW < W) {
        rs_c = colSig(w0 + TW);
        emit(w0 + TW - 1, rs_m2, rs_m1, rs_c, TrueT{}, TrueT{});
    } else {
        emit(w0 + TW - 1, rs_m2, rs_m1, rs_c, TrueT{}, FalseT{});
    }
}

__global__ __launch_bounds__(256, 8) void bsign_dw3x3_r4c4(
        const float* __restrict__ x, const float* __restrict__ k,
        float* __restrict__ out) {
    const int c0 = (threadIdx.x & 63) << 2;   // 4 channels/lane, full C per wave
    const int wq = threadIdx.x >> 6;          // wave -> row group within block
    const int h0 = blockIdx.y * (4 * R) + wq * R;
    const int w0 = blockIdx.x * TW;
    const int n  = blockIdx.z;

    if (h0 == 0)           run_tile<true,  false>(x, k, out, n, h0, w0, c0);
    else if (h0 == H - R)  run_tile<false, true >(x, k, out, n, h0, w0, c0);
    else                   run_tile<false, false>(x, k, out, n, h0, w0, c0);
}

extern "C" void kernel_launch(void* const* d_in, const int* in_sizes, int n_in,
                              void* d_out, int out_size, void* d_ws, size_t ws_size,
                              hipStream_t stream) {
    const float* x = (const float*)d_in[0];   // (16,112,112,256) f32
    const float* k = (const float*)d_in[1];   // (3,3,256,1) f32
    float* out = (float*)d_out;               // (16,112,112,256) f32

    dim3 grid(W / TW, H / (4 * R), N);        // (14, 7, 16)
    bsign_dw3x3_r4c4<<<grid, 256, 0, stream>>>(x, k, out);
}

// Round 4
// 359.310 us; speedup vs baseline: 1.0295x; 1.0295x over previous
//
#include <hip/hip_runtime.h>

// Binarized depthwise 3x3 conv, stride 1, SAME, NHWC, sign(0)=+1.
// x: (16,112,112,256) f32, kernel: (3,3,256,1) f32, out: (16,112,112,256) f32.
//
// Round 7: LDS sign staging to decouple load issue from consumption.
// Rounds 0-3 all pinned at 2.6-3.0 TB/s HBM with VALUBusy 13-22%:
// latency-bound because every global load fed an immediate sign-extract
// chain (~1 outstanding load/wave). Here a block (4 waves) stages the
// sign bits of an 18-row x 16-col x 256-ch input tile into LDS first:
// each wave packs 4 columns, each column = 18 INDEPENDENT 1KB uint4 loads
// (pack + one ds_write_b128 at the end), so tens of KB/wave are in flight.
// After one barrier, the popc phase runs entirely out of LDS.
// Read amplification also drops: 18/16 rows x 16/14 cols = 1.29x input
// (vs 1.875x in rounds 4-6, 3x in the round-0-3 family).
//
// sig[ci*C + ch] bit p = signbit x[n, h0-1+p, w0-1+ci, ch], p in [0,17].
// Missing border rows stay 0 and are masked out per output row r by
// bm[r]; missing border columns drop the whole kernel-column term
// (template tag at the two edge emits). nt = nterms * popc(bm[r]).
// Output row r of wave wq uses window bits [4wq+r, 4wq+r+2]; sig is
// pre-shifted by 4wq at ds_read so the window shift is just >>r.

constexpr int N = 16, H = 112, W = 112, C = 256;
constexpr int TW = 14;          // output cols per block; W/TW = 8
constexpr int COLS = TW + 2;    // staged sig columns
constexpr int RW = 4;           // output rows per wave; 4 waves -> 16 rows/block

typedef float f32x4 __attribute__((ext_vector_type(4)));

struct TrueT  { static constexpr bool value = true;  };
struct FalseT { static constexpr bool value = false; };

__global__ __launch_bounds__(256, 4) void bsign_dw3x3_lds(
        const float* __restrict__ x, const float* __restrict__ k,
        float* __restrict__ out) {
    __shared__ unsigned sig[COLS * C];   // 16 KB

    const int lane = threadIdx.x & 63;
    const int wq   = threadIdx.x >> 6;
    const int c0   = lane << 2;          // 4 channels/lane, full C per wave
    const int h0   = blockIdx.y * 16;
    const int w0   = blockIdx.x * TW;
    const int n    = blockIdx.z;

    // Kernel sign codes k3[j][ch]: bit i = signbit k[i][j].
    unsigned k3[3][4] = {{0,0,0,0},{0,0,0,0},{0,0,0,0}};
#pragma unroll
    for (int t = 0; t < 9; ++t) {
        const uint4 kv = *reinterpret_cast<const uint4*>(k + t * C + c0);
        const int kr = t / 3, kj = t % 3;
        k3[kj][0] |= (kv.x >> 31) << kr;
        k3[kj][1] |= (kv.y >> 31) << kr;
        k3[kj][2] |= (kv.z >> 31) << kr;
        k3[kj][3] |= (kv.w >> 31) << kr;
    }

    const size_t rowstride = (size_t)W * C;

    // ---- Phase 1: stage sig columns. Wave wq owns ci = 4wq .. 4wq+3. ----
    const bool ptop = (h0 > 0);        // row h0-1  exists (p=0)
    const bool pbot = (h0 + 16 < H);   // row h0+16 exists (p=17)
#pragma unroll
    for (int q = 0; q < 4; ++q) {
        const int ci   = (wq << 2) + q;
        const int xcol = w0 - 1 + ci;
        unsigned s0 = 0, s1 = 0, s2 = 0, s3 = 0;
        if (xcol >= 0 && xcol < W) {   // wave-uniform
            const float* cp = x + (size_t)(n * H + h0 - 1) * rowstride
                                + (size_t)xcol * C + c0;
#pragma unroll
            for (int p = 0; p < 18; ++p) {
                if (p == 0  && !ptop) continue;
                if (p == 17 && !pbot) continue;
                const uint4 v = *reinterpret_cast<const uint4*>(
                    cp + (size_t)p * rowstride);
                s0 |= (v.x >> 31) << p;
                s1 |= (v.y >> 31) << p;
                s2 |= (v.z >> 31) << p;
                s3 |= (v.w >> 31) << p;
            }
        }
        uint4 sv; sv.x = s0; sv.y = s1; sv.z = s2; sv.w = s3;
        *reinterpret_cast<uint4*>(&sig[ci * C + c0]) = sv;   // ds_write_b128
    }
    __syncthreads();

    // ---- Phase 2: popc compute from LDS. ----
    const int hbase = h0 + (wq << 2);
    unsigned bm[RW]; int nrr[RW];
#pragma unroll
    for (int r = 0; r < RW; ++r) {
        const int h = hbase + r;
        unsigned b = 7u;
        if (h == 0)     b &= ~1u;
        if (h == H - 1) b &= ~4u;
        bm[r]  = b;
        nrr[r] = (b == 7u) ? 3 : 2;
    }
    const int sh0 = wq << 2;
    float* obase = out + (size_t)(n * H + hbase) * rowstride
                       + (size_t)w0 * C + c0;

    unsigned m2[4], m1[4], cc[4];
    auto ldsig = [&](int ci, unsigned d[4]) {
        const uint4 v = *reinterpret_cast<const uint4*>(&sig[ci * C + c0]);
        d[0] = v.x >> sh0; d[1] = v.y >> sh0;
        d[2] = v.z >> sh0; d[3] = v.w >> sh0;
    };
    auto emit = [&](int wo, const unsigned a[4], const unsigned bc[4],
                    const unsigned ce[4], auto jt0, auto jt2) {
        constexpr int NT = (decltype(jt0)::value ? 1 : 0) + 1
                         + (decltype(jt2)::value ? 1 : 0);
        float* orow = obase + (size_t)wo * C;
#pragma unroll
        for (int r = 0; r < RW; ++r) {
            const unsigned b = bm[r];
            int n0 = 0, n1 = 0, n2 = 0, n3 = 0;
            auto term = [&](const unsigned s[4], const unsigned kk[4]) {
                n0 += __popc(((s[0] >> r) ^ kk[0]) & b);
                n1 += __popc(((s[1] >> r) ^ kk[1]) & b);
                n2 += __popc(((s[2] >> r) ^ kk[2]) & b);
                n3 += __popc(((s[3] >> r) ^ kk[3]) & b);
            };
            if constexpr (decltype(jt0)::value) term(a, k3[0]);
            term(bc, k3[1]);
            if constexpr (decltype(jt2)::value) term(ce, k3[2]);
            const int nt = NT * nrr[r];
            f32x4 ov;
            ov[0] = (float)(nt - 2 * n0);
            ov[1] = (float)(nt - 2 * n1);
            ov[2] = (float)(nt - 2 * n2);
            ov[3] = (float)(nt - 2 * n3);
            __builtin_nontemporal_store(ov,
                reinterpret_cast<f32x4*>(orow + (size_t)r * rowstride));
        }
    };

    ldsig(0, m2); ldsig(1, m1); ldsig(2, cc);
    if (w0 > 0) emit(0, m2, m1, cc, TrueT{},  TrueT{});
    else        emit(0, m2, m1, cc, FalseT{}, TrueT{});
#pragma unroll
    for (int ch = 0; ch < 4; ++ch) { m2[ch] = m1[ch]; m1[ch] = cc[ch]; }

#pragma unroll
    for (int wo = 1; wo < TW - 1; ++wo) {
        ldsig(wo + 2, cc);
        emit(wo, m2, m1, cc, TrueT{}, TrueT{});
#pragma unroll
        for (int ch = 0; ch < 4; ++ch) { m2[ch] = m1[ch]; m1[ch] = cc[ch]; }
    }

    ldsig(TW + 1, cc);
    if (w0 + TW < W) emit(TW - 1, m2, m1, cc, TrueT{}, TrueT{});
    else             emit(TW - 1, m2, m1, cc, TrueT{}, FalseT{});
}

extern "C" void kernel_launch(void* const* d_in, const int* in_sizes, int n_in,
                              void* d_out, int out_size, void* d_ws, size_t ws_size,
                              hipStream_t stream) {
    const float* x = (const float*)d_in[0];   // (16,112,112,256) f32
    const float* k = (const float*)d_in[1];   // (3,3,256,1) f32
    float* out = (float*)d_out;               // (16,112,112,256) f32

    dim3 grid(W / TW, H / 16, N);             // (8, 7, 16) = 896 blocks
    bsign_dw3x3_lds<<<grid, 256, 0, stream>>>(x, k, out);
}

// Round 5
// 356.887 us; speedup vs baseline: 1.0365x; 1.0068x over previous
//
#include <hip/hip_runtime.h>

// Binarized depthwise 3x3 conv, stride 1, SAME, NHWC, sign(0)=+1.
// x: (16,112,112,256) f32, kernel: (3,3,256,1) f32, out: (16,112,112,256) f32.
//
// Round 8: ROW-LINEAR global streams. Rounds 0-7 all pinned at ~125-145 us
// with HBM bytes ~330-380 MB regardless of requested volume, occupancy, or
// per-wave MLP -- but fill (6.5 TB/s) and 1:1 float4 copy (6.29 TB/s) hit
// the ceiling on this chip. The shared flaw: all variants issued global
// loads down image columns (1 KB chunks at 112 KB stride) and stores the
// same way -> DRAM page thrash. This round keeps round-7's LDS staging but
// swaps loop orders so both streams are row-major:
//   phase 1: p (image row) outer, q (column) inner -> each wave issues
//            4 KB contiguous per row, block covers 16 KB contiguous.
//   phase 2: r (output row) outer, wo inner -> 14 KB linear store runs.
//
// sig[ci*C + ch] bit p = signbit x[n, h0-1+p, w0-1+ci, ch], p in [0,17].
// Border rows stay 0 and are masked per output row by the 3-bit window
// mask b; border columns are zeroed at the two edge terms of the slide.
// Output row r of wave wq uses window bits [4wq+r .. 4wq+r+2]; the ds_read
// result is shifted once by sh = 4wq + r (r is loop-constant).

constexpr int N = 16, H = 112, W = 112, C = 256;
constexpr int TW = 14;          // output cols per block; W/TW = 8
constexpr int COLS = TW + 2;    // staged sig columns
constexpr int RW = 4;           // output rows per wave; 4 waves -> 16 rows/block

typedef float f32x4 __attribute__((ext_vector_type(4)));

__global__ __launch_bounds__(256, 4) void bsign_dw3x3_rowstream(
        const float* __restrict__ x, const float* __restrict__ k,
        float* __restrict__ out) {
    __shared__ unsigned sig[COLS * C];   // 16 KB

    const int lane = threadIdx.x & 63;
    const int wq   = threadIdx.x >> 6;
    const int c0   = lane << 2;          // 4 channels/lane, full C per wave
    const int h0   = blockIdx.y * 16;
    const int w0   = blockIdx.x * TW;
    const int n    = blockIdx.z;

    const size_t rowstride = (size_t)W * C;
    const bool ptop = (h0 > 0);          // row h0-1  exists (p=0)
    const bool pbot = (h0 + 16 < H);     // row h0+16 exists (p=17)

    // ---- Phase 1: stage sig columns, ROW-MAJOR issue order. ----
    // Wave wq owns sig columns ci = 4wq..4wq+3 (4 KB contiguous per row).
    const int ciB = wq << 2;
    const float* xbase = x + (size_t)(n * H + h0 - 1) * rowstride + c0;
    bool cv[4];
    const float* cp[4];
#pragma unroll
    for (int q = 0; q < 4; ++q) {
        const int xc = w0 - 1 + ciB + q;
        cv[q] = (xc >= 0 && xc < W);     // wave-uniform
        cp[q] = xbase + (ptrdiff_t)xc * (ptrdiff_t)C;
    }
    unsigned sq[4][4] = {{0,0,0,0},{0,0,0,0},{0,0,0,0},{0,0,0,0}};
#pragma unroll
    for (int p = 0; p < 18; ++p) {
        if (p == 0  && !ptop) continue;
        if (p == 17 && !pbot) continue;
        const size_t ro = (size_t)p * rowstride;
#pragma unroll
        for (int q = 0; q < 4; ++q) {
            if (cv[q]) {
                const uint4 v = *reinterpret_cast<const uint4*>(cp[q] + ro);
                sq[q][0] |= (v.x >> 31) << p;
                sq[q][1] |= (v.y >> 31) << p;
                sq[q][2] |= (v.z >> 31) << p;
                sq[q][3] |= (v.w >> 31) << p;
            }
        }
    }
#pragma unroll
    for (int q = 0; q < 4; ++q) {
        uint4 sv; sv.x = sq[q][0]; sv.y = sq[q][1]; sv.z = sq[q][2]; sv.w = sq[q][3];
        *reinterpret_cast<uint4*>(&sig[(ciB + q) * C + c0]) = sv;
    }

    // Kernel sign codes k3[j][ch]: bit i = signbit k[i][j]. (Issued here so
    // they overlap the phase-1 drain / barrier.)
    unsigned k3[3][4] = {{0,0,0,0},{0,0,0,0},{0,0,0,0}};
#pragma unroll
    for (int t = 0; t < 9; ++t) {
        const uint4 kv = *reinterpret_cast<const uint4*>(k + t * C + c0);
        const int kr = t / 3, kj = t % 3;
        k3[kj][0] |= (kv.x >> 31) << kr;
        k3[kj][1] |= (kv.y >> 31) << kr;
        k3[kj][2] |= (kv.z >> 31) << kr;
        k3[kj][3] |= (kv.w >> 31) << kr;
    }
    __syncthreads();

    // ---- Phase 2: popc compute, ROW-MAJOR store order. ----
    const int hbase = h0 + (wq << 2);
    float* obase = out + (size_t)(n * H + hbase) * rowstride
                       + (size_t)w0 * C + c0;
    const bool ledge = (w0 == 0), redge = (w0 + TW == W);

#pragma unroll
    for (int r = 0; r < RW; ++r) {
        const int h  = hbase + r;
        const unsigned b = (h == 0) ? 6u : (h == H - 1) ? 3u : 7u;
        const int nr = (h == 0 || h == H - 1) ? 2 : 3;
        const int sh = (wq << 2) + r;
        float* orow = obase + (size_t)r * rowstride;

        // Sliding per-term values: t_j(ci) = contribution of sig col ci as
        // kernel col j. out(wo) = t0(wo) + t1(wo+1) + t2(wo+2)  [ci-indexed].
        int t0m2[4], t0m1[4], t1m1[4], tj0[4], tj1[4], tj2[4];

        auto tcol = [&](int ci) {
            const uint4 v = *reinterpret_cast<const uint4*>(&sig[ci * C + c0]);
            const unsigned d[4] = {v.x >> sh, v.y >> sh, v.z >> sh, v.w >> sh};
#pragma unroll
            for (int ch = 0; ch < 4; ++ch) {
                tj0[ch] = nr - 2 * __popc((d[ch] ^ k3[0][ch]) & b);
                tj1[ch] = nr - 2 * __popc((d[ch] ^ k3[1][ch]) & b);
                tj2[ch] = nr - 2 * __popc((d[ch] ^ k3[2][ch]) & b);
            }
        };

        if (ledge) {
#pragma unroll
            for (int ch = 0; ch < 4; ++ch) t0m2[ch] = 0;
        } else {
            tcol(0);
#pragma unroll
            for (int ch = 0; ch < 4; ++ch) t0m2[ch] = tj0[ch];
        }
        tcol(1);
#pragma unroll
        for (int ch = 0; ch < 4; ++ch) { t0m1[ch] = tj0[ch]; t1m1[ch] = tj1[ch]; }

#pragma unroll
        for (int ci = 2; ci < COLS; ++ci) {
            if (ci == COLS - 1 && redge) {
#pragma unroll
                for (int ch = 0; ch < 4; ++ch) tj2[ch] = 0;
            } else {
                tcol(ci);
            }
            f32x4 ov;
#pragma unroll
            for (int ch = 0; ch < 4; ++ch)
                ov[ch] = (float)(t0m2[ch] + t1m1[ch] + tj2[ch]);
            __builtin_nontemporal_store(ov,
                reinterpret_cast<f32x4*>(orow + (size_t)(ci - 2) * C));
#pragma unroll
            for (int ch = 0; ch < 4; ++ch) {
                t0m2[ch] = t0m1[ch]; t0m1[ch] = tj0[ch]; t1m1[ch] = tj1[ch];
            }
        }
    }
}

extern "C" void kernel_launch(void* const* d_in, const int* in_sizes, int n_in,
                              void* d_out, int out_size, void* d_ws, size_t ws_size,
                              hipStream_t stream) {
    const float* x = (const float*)d_in[0];   // (16,112,112,256) f32
    const float* k = (const float*)d_in[1];   // (3,3,256,1) f32
    float* out = (float*)d_out;               // (16,112,112,256) f32

    dim3 grid(W / TW, H / 16, N);             // (8, 7, 16) = 896 blocks
    bsign_dw3x3_rowstream<<<grid, 256, 0, stream>>>(x, k, out);
}